// Round 15
// baseline (147.861 us; speedup 1.0000x reference)
//
#include <hip/hip_runtime.h>
#include <hip/hip_bf16.h>

// ModuleCorefProp2: coref propagation, B=1, K=512, N=16384, D=512, H=64, NB=10, 1 iter.
// R15 = R14 + occupancy-by-waves probe: k_pair64 now 1024 threads / 16 waves on the
// SAME 256x256 tile (wave grid 4x4, acc 2x2; per-wave chunk chain halves; 4 waves/SIMD
// instead of 2). pair2 = k_pair2 unchanged (45us control).

typedef __bf16 bf16;
typedef bf16 bf16x8 __attribute__((ext_vector_type(8)));
typedef float f32x4 __attribute__((ext_vector_type(4)));
typedef float f32x16 __attribute__((ext_vector_type(16)));

#define MFMA16(a, b, c) __builtin_amdgcn_mfma_f32_16x16x32_bf16((a), (b), (c), 0, 0, 0)
#define MFMA32(a, b, c) __builtin_amdgcn_mfma_f32_32x32x16_bf16((a), (b), (c), 0, 0, 0)

__device__ __forceinline__ void gll16(const bf16* g, bf16* lds) {
  __builtin_amdgcn_global_load_lds(
      (const __attribute__((address_space(1))) unsigned int*)g,
      (__attribute__((address_space(3))) unsigned int*)lds, 16, 0, 0);
}

// ---------------------------------------------------------------- prep
__global__ void k_prep(const float* __restrict__ sv,
                       const float* __restrict__ Wl, const float* __restrict__ Wr,
                       const float* __restrict__ Wg1, const float* __restrict__ Wg2,
                       const float* __restrict__ de, const float* __restrict__ Wd,
                       const float* __restrict__ bd, const float* __restrict__ bl,
                       const float* __restrict__ br, const float* __restrict__ bg1,
                       const float* __restrict__ bg2, const float* __restrict__ Wp,
                       bf16* __restrict__ u1, bf16* __restrict__ wext,
                       float* __restrict__ bext, bf16* __restrict__ wgbot,
                       float* __restrict__ dtab, bf16* __restrict__ wpTb)
{
  const int total = 262144 + 589824 + 1152 + 524288 + 640 + 32768;
  for (int idx0 = blockIdx.x * 256 + threadIdx.x; idx0 < total; idx0 += 2048 * 256) {
    int k = idx0;
    if (k < 262144) {                 // u -> bf16
      u1[k] = (bf16)sv[k];
      continue;
    }
    k -= 262144;
    if (k < 589824) {                 // wext = [Wl|Wr|Wg1top|Wg2top] bf16 [512][1152]
      int d = k / 1152, n = k % 1152;
      float v;
      if (n < 64) v = Wl[d * 64 + n];
      else if (n < 128) v = Wr[d * 64 + n - 64];
      else if (n < 640) v = Wg1[d * 512 + (n - 128)];
      else v = Wg2[d * 512 + (n - 640)];
      wext[k] = (bf16)v;
      continue;
    }
    k -= 589824;
    if (k < 1152) {                   // bext = [bl|br|bg1|bg2]
      float v;
      if (k < 64) v = bl[k];
      else if (k < 128) v = br[k - 64];
      else if (k < 640) v = bg1[k - 128];
      else v = bg2[k - 640];
      bext[k] = v;
      continue;
    }
    k -= 1152;
    if (k < 524288) {                 // wgbot bf16 [2][512][512] (bottom halves)
      wgbot[k] = (bf16)((k < 262144) ? Wg1[262144 + k] : Wg2[k]);
      continue;
    }
    k -= 524288;
    if (k < 640) {                    // dtab[NB][64] = dist_emb@Wd + bd
      int b_ = k >> 6, h = k & 63;
      float s = bd[h];
      for (int e = 0; e < 64; ++e) s += de[b_ * 64 + e] * Wd[e * 64 + h];
      dtab[k] = s;
      continue;
    }
    k -= 640;
    {                                 // wpTb[h][d] = Wp[d][h], bf16 [64][512]
      int h = k >> 9, d = k & 511;
      wpTb[k] = (bf16)Wp[d * 64 + h];
    }
  }
}

// ---------------------------------------------------------------- generic GEMM
__global__ __launch_bounds__(256, 2) void k_gemm(
    const bf16* __restrict__ A, int lda, long asz,
    const bf16* __restrict__ B, int ldb, long bsz,
    float* __restrict__ C, int ldc, long csz,
    const float* __restrict__ bias, int K,
    const float* __restrict__ addm, long addm_zs, int addm_ld,
    bf16* __restrict__ xout)
{
  __shared__ bf16 As[64 * 40];
  __shared__ bf16 Bs[64 * 40];
  const int t = threadIdx.x, lane = t & 63, wave = t >> 6;
  const int tc = blockIdx.x, tr = blockIdx.y, z = blockIdx.z;
  A += (long)z * asz; B += (long)z * bsz; C += (long)z * csz;
  const int wr = wave >> 1, wc = wave & 1;
  const int arow = t >> 2, aslot = t & 3;
  const int s = lane >> 4, rr = lane & 15;
  f32x4 acc00 = {}, acc01 = {}, acc10 = {}, acc11 = {};
  const int nk = K >> 5;
  for (int kk = 0; kk < nk; ++kk) {
    __syncthreads();
    *(uint4*)&As[arow * 40 + aslot * 8] =
        *(const uint4*)(A + (long)(tr * 64 + arow) * lda + kk * 32 + aslot * 8);
    {
      const bf16* bsrc = B + (long)(kk * 32 + aslot * 8) * ldb + tc * 64 + arow;
      bf16x8 tv;
#pragma unroll
      for (int e = 0; e < 8; ++e) tv[e] = bsrc[(long)e * ldb];
      *(bf16x8*)&Bs[arow * 40 + aslot * 8] = tv;
    }
    __syncthreads();
    bf16x8 a0 = *(const bf16x8*)&As[(wr * 32 + rr) * 40 + s * 8];
    bf16x8 a1 = *(const bf16x8*)&As[(wr * 32 + 16 + rr) * 40 + s * 8];
    bf16x8 b0 = *(const bf16x8*)&Bs[(wc * 32 + rr) * 40 + s * 8];
    bf16x8 b1 = *(const bf16x8*)&Bs[(wc * 32 + 16 + rr) * 40 + s * 8];
    acc00 = MFMA16(a0, b0, acc00);
    acc01 = MFMA16(a0, b1, acc01);
    acc10 = MFMA16(a1, b0, acc10);
    acc11 = MFMA16(a1, b1, acc11);
  }
#pragma unroll
  for (int mf = 0; mf < 2; ++mf) {
#pragma unroll
    for (int nf = 0; nf < 2; ++nf) {
      f32x4 v = mf == 0 ? (nf == 0 ? acc00 : acc01) : (nf == 0 ? acc10 : acc11);
      int col = tc * 64 + wc * 32 + nf * 16 + rr;
      float bi = bias ? bias[col] : 0.f;
      int row0 = tr * 64 + wr * 32 + mf * 16 + s * 4;
#pragma unroll
      for (int r = 0; r < 4; ++r) {
        int row = row0 + r;
        float val = v[r] + bi;
        if (addm) val += addm[z * addm_zs + (long)row * addm_ld + col];
        C[(long)row * ldc + col] = val;
        if (xout) xout[(long)row * 512 + col] = (bf16)val;
      }
    }
  }
}

// ---------------------------------------------------------------- pair64 (R15: 1024 thr)
// 256m x 256n tile, K-chunk 64, grid (2,128). 16 waves: wm=w>>2 (i index 0..3),
// wn=w&3 (64-col block). Per wave acc 2x2 f32x16. 2 gll + 2 A-build units/thread.
__global__ __launch_bounds__(1024, 1) void k_pair64(
    const bf16* __restrict__ Ubf, const float* __restrict__ Uf,
    const bf16* __restrict__ wpTb, const float* __restrict__ LR, int ldlr,
    const float* __restrict__ dtabg, const int* __restrict__ sb,
    const float* __restrict__ ss, const float* __restrict__ Wo,
    const float* __restrict__ bo, float* __restrict__ cs,
    const float* __restrict__ copysrc, float* __restrict__ copydst, int docopy)
{
  __shared__ bf16 Apan[2][256 * 64];   // 2 x 32KB
  __shared__ bf16 Bpan[2][256 * 64];   // 2 x 32KB
  __shared__ float dtsp[10 * 68];
  __shared__ int sbt[256];

  const int t = threadIdx.x;
  const int l = t & 63;
  const int w = t >> 6;                // 0..15
  const int wm = w >> 2, wn = w & 3;
  const int hi = l >> 5, l31 = l & 31;
  const int jb = blockIdx.x;           // 0..1
  const int mt = blockIdx.y;           // 0..127
  const int i0 = mt * 4;
  const int i = i0 + wm;

  for (int idx = t; idx < 640; idx += 1024)
    dtsp[(idx >> 6) * 68 + (idx & 63)] = dtabg[idx];
  if (t < 256) sbt[t] = sb[jb * 256 + t];

  // B gll: 2 units/thread. unit u=q*1024+t: row r=u>>3, slot c=u&7, src k-slot c^(r&7).
  const bf16* bsrcq[2];
  bf16* bdstq[2];
#pragma unroll
  for (int q = 0; q < 2; ++q) {
    int u = q * 1024 + t;
    int r = u >> 3, c = u & 7;
    bsrcq[q] = Ubf + (long)(jb * 256 + r) * 512 + ((c ^ (r & 7)) * 8);
    bdstq[q] = &Bpan[0][0] + q * 8192 + w * 512;   // + lane*16B implicit
  }
  // A build: 2 units/thread; row m: ii=m>>6, h=m&63.
  const float* uapq[2];
  const bf16* wppq[2];
  int awbq[2];
#pragma unroll
  for (int q = 0; q < 2; ++q) {
    int u = q * 1024 + t;
    int m = u >> 3, c = u & 7;
    int koff = (c ^ (m & 7)) * 8;
    uapq[q] = Uf + (long)(i0 + (m >> 6)) * 512 + koff;
    wppq[q] = wpTb + (long)(m & 63) * 512 + koff;
    awbq[q] = m * 128 + c * 16;
  }

  // fragment read byte-offsets: r*128 + ((ks*2+hi)^(r&7))*16, ks=0..3
  int aoff[2][4], boff[2][4];
#pragma unroll
  for (int rf = 0; rf < 2; ++rf)
#pragma unroll
    for (int ks = 0; ks < 4; ++ks) {
      int r = wm * 64 + rf * 32 + l31;
      aoff[rf][ks] = r * 128 + (((ks * 2 + hi) ^ (r & 7)) * 16);
    }
#pragma unroll
  for (int cf = 0; cf < 2; ++cf)
#pragma unroll
    for (int ks = 0; ks < 4; ++ks) {
      int r = wn * 64 + cf * 32 + l31;
      boff[cf][ks] = r * 128 + (((ks * 2 + hi) ^ (r & 7)) * 16);
    }

  // ---- stage chunk 0 into buf 0
  {
#pragma unroll
    for (int q = 0; q < 2; ++q) gll16(bsrcq[q], bdstq[q]);
#pragma unroll
    for (int q = 0; q < 2; ++q) {
      float4 f0 = *(const float4*)uapq[q];
      float4 f1 = *(const float4*)(uapq[q] + 4);
      bf16x8 wv = *(const bf16x8*)wppq[q];
      bf16x8 v;
#pragma unroll
      for (int e = 0; e < 4; ++e) {
        v[e] = (bf16)(f0[e] * (float)wv[e]);
        v[e + 4] = (bf16)(f1[e] * (float)wv[e + 4]);
      }
      *(bf16x8*)((char*)&Apan[0][0] + awbq[q]) = v;
    }
  }
  asm volatile("s_waitcnt vmcnt(0)");
  __syncthreads();

  f32x16 acc[2][2] = {};

  for (int kc = 0; kc < 8; ++kc) {
    const int cur = kc & 1;
    float4 nf0[2], nf1[2];
    bf16x8 nwv[2];
    if (kc < 7) {                      // issue next-chunk loads (hide under compute)
#pragma unroll
      for (int q = 0; q < 2; ++q)
        gll16(bsrcq[q] + (kc + 1) * 64, bdstq[q] + (cur ^ 1) * 16384);
#pragma unroll
      for (int q = 0; q < 2; ++q) {
        nf0[q] = *(const float4*)(uapq[q] + (kc + 1) * 64);
        nf1[q] = *(const float4*)(uapq[q] + (kc + 1) * 64 + 4);
        nwv[q] = *(const bf16x8*)(wppq[q] + (kc + 1) * 64);
      }
    }
    const char* Ab = (const char*)&Apan[cur][0];
    const char* Bb = (const char*)&Bpan[cur][0];
#pragma unroll
    for (int ks = 0; ks < 4; ++ks) {
      bf16x8 af0 = *(const bf16x8*)(Ab + aoff[0][ks]);
      bf16x8 af1 = *(const bf16x8*)(Ab + aoff[1][ks]);
      bf16x8 bf0 = *(const bf16x8*)(Bb + boff[0][ks]);
      bf16x8 bf1 = *(const bf16x8*)(Bb + boff[1][ks]);
      __builtin_amdgcn_s_setprio(1);
      acc[0][0] = MFMA32(af0, bf0, acc[0][0]);
      acc[0][1] = MFMA32(af0, bf1, acc[0][1]);
      acc[1][0] = MFMA32(af1, bf0, acc[1][0]);
      acc[1][1] = MFMA32(af1, bf1, acc[1][1]);
      __builtin_amdgcn_s_setprio(0);
    }
    if (kc < 7) {
      asm volatile("s_waitcnt vmcnt(0)");
      char* Ad = (char*)&Apan[cur ^ 1][0];
#pragma unroll
      for (int q = 0; q < 2; ++q) {
        bf16x8 v;
#pragma unroll
        for (int e = 0; e < 4; ++e) {
          v[e] = (bf16)(nf0[q][e] * (float)nwv[q][e]);
          v[e + 4] = (bf16)(nf1[q][e] * (float)nwv[q][e + 4]);
        }
        *(bf16x8*)(Ad + awbq[q]) = v;
      }
    }
    __syncthreads();
  }

  // ---- epilogue
  float4 wo_t[2][4], lf_t[2][4];
#pragma unroll
  for (int rf = 0; rf < 2; ++rf)
#pragma unroll
    for (int g = 0; g < 4; ++g) {
      wo_t[rf][g] = *(const float4*)&Wo[rf * 32 + 4 * hi + 8 * g];
      lf_t[rf][g] = *(const float4*)&LR[(long)i * ldlr + rf * 32 + 4 * hi + 8 * g];
    }
  const float ssi = ss[i];
  const int sbi = sb[i];
  const float bo0 = bo[0];
#pragma unroll
  for (int cf = 0; cf < 2; ++cf) {
    int jl = wn * 64 + cf * 32 + l31;
    int j = jb * 256 + jl;
    int dd = sbi - sbt[jl];
    int ad = dd < 0 ? -dd : dd;
    int bkt = ad < 5 ? ad : (31 - __clz(ad)) + 3;
    bkt = bkt > 9 ? 9 : bkt;
    float ssj = ss[j];
    float sum = 0.f;
#pragma unroll
    for (int rf = 0; rf < 2; ++rf) {
#pragma unroll
      for (int g = 0; g < 4; ++g) {
        float4 dt4 = *(const float4*)&dtsp[bkt * 68 + rf * 32 + 4 * hi + 8 * g];
        float4 rt4 = *(const float4*)&LR[(long)j * ldlr + 64 + rf * 32 + 4 * hi + 8 * g];
#pragma unroll
        for (int e = 0; e < 4; ++e) {
          float v = acc[rf][cf][g * 4 + e] + lf_t[rf][g][e] + rt4[e] + dt4[e];
          v = fmaxf(v, 0.f);
          sum += v * wo_t[rf][g][e];
        }
      }
    }
    sum += __shfl_xor(sum, 32);
    float val = (j == i) ? 0.f : (sum + bo0 + ssi + ssj);
    if (hi == 0) cs[(long)i * 512 + j] = val;
  }

  if (docopy) {
    const float4* s4 = (const float4*)copysrc;
    float4* d4 = (float4*)copydst;
    int idx = (mt * 2 + jb) * 1024 + t;   // 262144 threads
#pragma unroll
    for (int q = 0; q < 8; ++q)
      d4[(long)q * 262144 + idx] = s4[(long)q * 262144 + idx];
  }
}

// ---------------------------------------------------------------- pair2 (R12 proven)
#define P2_BUILD(DST, A00, A01, A10, A11, W0, W1)                \
  {                                                              \
    bf16x8 v0, v1;                                               \
    _Pragma("unroll") for (int e = 0; e < 4; ++e) {              \
      v0[e] = (bf16)((A00)[e] * (float)(W0)[e]);                 \
      v0[e + 4] = (bf16)((A01)[e] * (float)(W0)[e + 4]);         \
      v1[e] = (bf16)((A10)[e] * (float)(W1)[e]);                 \
      v1[e + 4] = (bf16)((A11)[e] * (float)(W1)[e + 4]);         \
    }                                                            \
    *(bf16x8*)((DST) + awb0) = v0;                               \
    *(bf16x8*)((DST) + awb1) = v1;                               \
  }

#define P2_ITER(KC, bA00, bA01, bA10, bA11, bW0, bW1, rA00, rA01, rA10, rA11, rW0, rW1) \
  {                                                                                     \
    const int bcur = (KC) % 3, bnxt = ((KC) + 1) % 3, bpre = ((KC) + 2) % 3;            \
    asm volatile("s_waitcnt lgkmcnt(0)");                                               \
    asm volatile("s_waitcnt vmcnt(14)");                                                \
    __builtin_amdgcn_sched_barrier(0);                                                  \
    __builtin_amdgcn_s_barrier();                                                       \
    const char* Ab = Abase + bcur * 16384;                                              \
    const char* Bb = Bbase + bcur * 16384;                                              \
    _Pragma("unroll") for (int ks = 0; ks < 2; ++ks) {                                  \
      bf16x8 af0 = *(const bf16x8*)(Ab + aoff[0][ks]);                                  \
      bf16x8 af1 = *(const bf16x8*)(Ab + aoff[1][ks]);                                  \
      bf16x8 bf0 = *(const bf16x8*)(Bb + boff[0][ks]);                                  \
      bf16x8 bf1 = *(const bf16x8*)(Bb + boff[1][ks]);                                  \
      bf16x8 bf2 = *(const bf16x8*)(Bb + boff[2][ks]);                                  \
      bf16x8 bf3 = *(const bf16x8*)(Bb + boff[3][ks]);                                  \
      __builtin_amdgcn_s_setprio(1);                                                    \
      acc[0][0] = MFMA32(af0, bf0, acc[0][0]);                                          \
      acc[0][1] = MFMA32(af0, bf1, acc[0][1]);                                          \
      acc[0][2] = MFMA32(af0, bf2, acc[0][2]);                                          \
      acc[0][3] = MFMA32(af0, bf3, acc[0][3]);                                          \
      acc[1][0] = MFMA32(af1, bf0, acc[1][0]);                                          \
      acc[1][1] = MFMA32(af1, bf1, acc[1][1]);                                          \
      acc[1][2] = MFMA32(af1, bf2, acc[1][2]);                                          \
      acc[1][3] = MFMA32(af1, bf3, acc[1][3]);                                          \
      __builtin_amdgcn_s_setprio(0);                                                    \
    }                                                                                   \
    if ((KC) < 15) { P2_BUILD(Abase + bnxt * 16384, bA00, bA01, bA10, bA11, bW0, bW1) } \
    if ((KC) < 14) {                                                                    \
      bf16* Bd = (bf16*)(Bbase + bpre * 16384);                                         \
      gll16(bsrc0 + ((KC) + 2) * 32, Bd + w * 512);                                     \
      gll16(bsrc1 + ((KC) + 2) * 32, Bd + 4096 + w * 512);                              \
      rA00 = *(const float4*)(ua0p + ((KC) + 2) * 32);                                  \
      rA01 = *(const float4*)(ua0p + ((KC) + 2) * 32 + 4);                              \
      rA10 = *(const float4*)(ua1p + ((KC) + 2) * 32);                                  \
      rA11 = *(const float4*)(ua1p + ((KC) + 2) * 32 + 4);                              \
      rW0 = *(const bf16x8*)(wp0p + ((KC) + 2) * 32);                                   \
      rW1 = *(const bf16x8*)(wp1p + ((KC) + 2) * 32);                                   \
    }                                                                                   \
  }

__global__ __launch_bounds__(512, 1) void k_pair2(
    const bf16* __restrict__ Ubf, const float* __restrict__ Uf,
    const bf16* __restrict__ wpTb, const float* __restrict__ LR, int ldlr,
    const float* __restrict__ dtabg, const int* __restrict__ sb,
    const float* __restrict__ ss, const float* __restrict__ Wo,
    const float* __restrict__ bo, float* __restrict__ cs)
{
  __shared__ bf16 Apan[3][256 * 32];
  __shared__ bf16 Bpan[3][256 * 32];
  __shared__ float dtsp[10 * 68];
  __shared__ int sbt[256];

  const int t = threadIdx.x;
  const int l = t & 63;
  const int w = t >> 6;
  const int wm = w >> 1, wn = w & 1;
  const int hi = l >> 5, l31 = l & 31;
  const int jb = blockIdx.x;
  const int mt = blockIdx.y;
  const int i0 = mt * 4;
  const int i = i0 + wm;

  for (int idx = t; idx < 640; idx += 512)
    dtsp[(idx >> 6) * 68 + (idx & 63)] = dtabg[idx];
  if (t < 256) sbt[t] = sb[jb * 256 + t];

  const bf16 *bsrc0, *bsrc1;
  {
    int r0 = t >> 2, c0 = t & 3;
    int r1 = 128 + (t >> 2);
    bsrc0 = Ubf + (long)(jb * 256 + r0) * 512 + ((c0 ^ ((r0 >> 1) & 3)) * 8);
    bsrc1 = Ubf + (long)(jb * 256 + r1) * 512 + ((c0 ^ ((r1 >> 1) & 3)) * 8);
  }
  const int ar0 = t >> 2, ar1 = 128 + (t >> 2), as0 = t & 3;
  const int awb0 = ar0 * 64 + ((as0 ^ ((ar0 >> 1) & 3)) * 16);
  const int awb1 = ar1 * 64 + ((as0 ^ ((ar1 >> 1) & 3)) * 16);
  const float* ua0p = Uf + (long)(i0 + (ar0 >> 6)) * 512 + as0 * 8;
  const float* ua1p = Uf + (long)(i0 + (ar1 >> 6)) * 512 + as0 * 8;
  const bf16* wp0p = wpTb + (long)(ar0 & 63) * 512 + as0 * 8;
  const bf16* wp1p = wpTb + (long)(ar1 & 63) * 512 + as0 * 8;

  int aoff[2][2], boff[4][2];
#pragma unroll
  for (int rf = 0; rf < 2; ++rf)
#pragma unroll
    for (int ks = 0; ks < 2; ++ks) {
      int r = wm * 64 + rf * 32 + l31;
      aoff[rf][ks] = r * 64 + (((ks * 2 + hi) ^ ((r >> 1) & 3)) * 16);
    }
#pragma unroll
  for (int cf = 0; cf < 4; ++cf)
#pragma unroll
    for (int ks = 0; ks < 2; ++ks) {
      int r = wn * 128 + cf * 32 + l31;
      boff[cf][ks] = r * 64 + (((ks * 2 + hi) ^ ((r >> 1) & 3)) * 16);
    }

  char* Abase = (char*)&Apan[0][0];
  char* Bbase = (char*)&Bpan[0][0];

  float4 aA00, aA01, aA10, aA11; bf16x8 wA0, wA1;
  float4 aB00, aB01, aB10, aB11; bf16x8 wB0, wB1;
  gll16(bsrc0, (bf16*)Bbase + w * 512);
  gll16(bsrc1, (bf16*)Bbase + 4096 + w * 512);
  aA00 = *(const float4*)ua0p;        aA01 = *(const float4*)(ua0p + 4);
  aA10 = *(const float4*)ua1p;        aA11 = *(const float4*)(ua1p + 4);
  wA0 = *(const bf16x8*)wp0p;         wA1 = *(const bf16x8*)wp1p;
  gll16(bsrc0 + 32, (bf16*)(Bbase + 16384) + w * 512);
  gll16(bsrc1 + 32, (bf16*)(Bbase + 16384) + 4096 + w * 512);
  aB00 = *(const float4*)(ua0p + 32); aB01 = *(const float4*)(ua0p + 36);
  aB10 = *(const float4*)(ua1p + 32); aB11 = *(const float4*)(ua1p + 36);
  wB0 = *(const bf16x8*)(wp0p + 32);  wB1 = *(const bf16x8*)(wp1p + 32);
  P2_BUILD(Abase, aA00, aA01, aA10, aA11, wA0, wA1)

  f32x16 acc[2][4] = {};

  for (int kq = 0; kq < 8; ++kq) {
    const int kc = kq * 2;
    P2_ITER(kc, aB00, aB01, aB10, aB11, wB0, wB1,
            aA00, aA01, aA10, aA11, wA0, wA1)
    P2_ITER(kc + 1, aA00, aA01, aA10, aA11, wA0, wA1,
            aB00, aB01, aB10, aB11, wB0, wB1)
  }

  float4 wo_t[2][4], lf_t[2][4];
#pragma unroll
  for (int rf = 0; rf < 2; ++rf)
#pragma unroll
    for (int g = 0; g < 4; ++g) {
      wo_t[rf][g] = *(const float4*)&Wo[rf * 32 + 4 * hi + 8 * g];
      lf_t[rf][g] = *(const float4*)&LR[(long)i * ldlr + rf * 32 + 4 * hi + 8 * g];
    }
  const float ssi = ss[i];
  const int sbi = sb[i];
  const float bo0 = bo[0];
#pragma unroll
  for (int cf = 0; cf < 4; ++cf) {
    int jl = wn * 128 + cf * 32 + l31;
    int j = jb * 256 + jl;
    int dd = sbi - sbt[jl];
    int ad = dd < 0 ? -dd : dd;
    int bkt = ad < 5 ? ad : (31 - __clz(ad)) + 3;
    bkt = bkt > 9 ? 9 : bkt;
    float ssj = ss[j];
    float sum = 0.f;
#pragma unroll
    for (int rf = 0; rf < 2; ++rf) {
#pragma unroll
      for (int g = 0; g < 4; ++g) {
        float4 dt4 = *(const float4*)&dtsp[bkt * 68 + rf * 32 + 4 * hi + 8 * g];
        float4 rt4 = *(const float4*)&LR[(long)j * ldlr + 64 + rf * 32 + 4 * hi + 8 * g];
#pragma unroll
        for (int e = 0; e < 4; ++e) {
          float v = acc[rf][cf][g * 4 + e] + lf_t[rf][g][e] + rt4[e] + dt4[e];
          v = fmaxf(v, 0.f);
          sum += v * wo_t[rf][g][e];
        }
      }
    }
    sum += __shfl_xor(sum, 32);
    float val = (j == i) ? 0.f : (sum + bo0 + ssi + ssj);
    if (hi == 0) cs[(long)i * 512 + j] = val;
  }
}

// ---------------------------------------------------------------- masked softmax rows
__global__ __launch_bounds__(64) void k_softmax(const float* __restrict__ cs,
                                                bf16* __restrict__ p12)
{
  int b = blockIdx.x, kind = b >> 9, i = b & 511, lane = threadIdx.x;
  const float* row = cs + i * 512;
  float v[8];
  float4 x0 = *(const float4*)(row + lane * 8);
  float4 x1 = *(const float4*)(row + lane * 8 + 4);
  v[0] = x0.x; v[1] = x0.y; v[2] = x0.z; v[3] = x0.w;
  v[4] = x1.x; v[5] = x1.y; v[6] = x1.z; v[7] = x1.w;
  bool any = (kind == 0) ? (i > 0) : (i < 511);
  bf16x8 ov;
  if (!any) {
    float u = 1.0f / 512.0f;
#pragma unroll
    for (int e = 0; e < 8; ++e) ov[e] = (bf16)u;
  } else {
    float m = -3.4e38f;
#pragma unroll
    for (int e = 0; e < 8; ++e) {
      int jj = lane * 8 + e;
      bool valid = (kind == 0) ? (jj < i) : (jj > i);
      if (valid) m = fmaxf(m, v[e]);
    }
    m = fmaxf(m, __shfl_xor(m, 1));  m = fmaxf(m, __shfl_xor(m, 2));
    m = fmaxf(m, __shfl_xor(m, 4));  m = fmaxf(m, __shfl_xor(m, 8));
    m = fmaxf(m, __shfl_xor(m, 16)); m = fmaxf(m, __shfl_xor(m, 32));
    float p[8]; float ssum = 0.f;
#pragma unroll
    for (int e = 0; e < 8; ++e) {
      int jj = lane * 8 + e;
      bool valid = (kind == 0) ? (jj < i) : (jj > i);
      p[e] = valid ? __expf(v[e] - m) : 0.f;
      ssum += p[e];
    }
    ssum += __shfl_xor(ssum, 1);  ssum += __shfl_xor(ssum, 2);
    ssum += __shfl_xor(ssum, 4);  ssum += __shfl_xor(ssum, 8);
    ssum += __shfl_xor(ssum, 16); ssum += __shfl_xor(ssum, 32);
    float inv = 1.0f / ssum;
#pragma unroll
    for (int e = 0; e < 8; ++e) ov[e] = (bf16)(p[e] * inv);
  }
  *(bf16x8*)(p12 + (long)b * 512 + lane * 8) = ov;
}

// ---------------------------------------------------------------- mid2: gate+ss2+lr2+scatter
__global__ __launch_bounds__(512) void k_mid2(
    const float* __restrict__ sv, const float* __restrict__ c12,
    const float* __restrict__ G12, const float* __restrict__ Wpr,
    const float* __restrict__ bpr, const bf16* __restrict__ wext, int ldw,
    const float* __restrict__ bext, const int* __restrict__ pi,
    const int* __restrict__ sl, float* __restrict__ upd,
    bf16* __restrict__ u2, float* __restrict__ ss2,
    float* __restrict__ lr2, float* __restrict__ out_all)
{
  __shared__ float upl[512];
  __shared__ float red[8];
  __shared__ float part2[4][128];
  const int i = blockIdx.x;
  const int t = threadIdx.x;
  const long ii = (long)i * 512 + t;

  float u = sv[ii], c1 = c12[ii], c2 = c12[262144 + ii];
  float g1 = 1.f / (1.f + __expf(-G12[ii]));
  float g2 = 1.f / (1.f + __expf(-G12[262144 + ii]));
  float up = g1 * u + (1.f - g1) * c1 + g2 * u + (1.f - g2) * c2;
  upd[ii] = up;
  u2[ii] = (bf16)up;
  upl[t] = up;
  if (i < sl[0]) out_all[(long)pi[i] * 512 + t] = up;

  float pd = up * Wpr[t];
  pd += __shfl_xor(pd, 1);  pd += __shfl_xor(pd, 2);  pd += __shfl_xor(pd, 4);
  pd += __shfl_xor(pd, 8);  pd += __shfl_xor(pd, 16); pd += __shfl_xor(pd, 32);
  if ((t & 63) == 0) red[t >> 6] = pd;
  __syncthreads();
  if (t == 0) {
    float s = 0.f;
#pragma unroll
    for (int e = 0; e < 8; ++e) s += red[e];
    ss2[i] = s + bpr[0];
  }

  const int n = t & 127, part = t >> 7;
  float s = 0.f;
  const int d0 = part * 128;
#pragma unroll 4
  for (int d2 = 0; d2 < 128; ++d2)
    s += upl[d0 + d2] * (float)wext[(long)(d0 + d2) * ldw + n];
  part2[part][n] = s;
  __syncthreads();
  if (t < 128)
    lr2[(long)i * 128 + t] =
        part2[0][t] + part2[1][t] + part2[2][t] + part2[3][t] + bext[t];
}

// ---------------------------------------------------------------- launch
extern "C" void kernel_launch(void* const* d_in, const int* in_sizes, int n_in,
                              void* d_out, int out_size, void* d_ws, size_t ws_size,
                              hipStream_t stream)
{
  const float* asv = (const float*)d_in[0];
  const float* sv = (const float*)d_in[1];
  const int* sb = (const int*)d_in[2];
  const float* sscore = (const float*)d_in[5];
  const int* pi = (const int*)d_in[6];
  const int* sl = (const int*)d_in[7];
  const float* Wl = (const float*)d_in[9];
  const float* bl = (const float*)d_in[10];
  const float* Wr = (const float*)d_in[11];
  const float* br = (const float*)d_in[12];
  const float* Wp = (const float*)d_in[13];
  const float* de = (const float*)d_in[14];
  const float* Wd = (const float*)d_in[15];
  const float* bd = (const float*)d_in[16];
  const float* Wo = (const float*)d_in[17];
  const float* bo = (const float*)d_in[18];
  const float* Wg1 = (const float*)d_in[19];
  const float* bg1 = (const float*)d_in[20];
  const float* Wg2 = (const float*)d_in[21];
  const float* bg2 = (const float*)d_in[22];
  const float* Wpr = (const float*)d_in[23];
  const float* bpr = (const float*)d_in[24];

  float* out_all = (float*)d_out;
  float* out_upd = out_all + 8388608;
  float* out_cs = out_all + 8650752;

  char* w = (char*)d_ws;
  size_t off = 0;
  auto take = [&](size_t bytes) -> void* {
    void* p = w + off;
    off = (off + bytes + 255) & ~(size_t)255;
    return p;
  };
  bf16* u1b = (bf16*)take(524288);
  bf16* u2b = (bf16*)take(524288);
  bf16* wext = (bf16*)take(1179648);
  float* bext = (float*)take(4608);
  bf16* wgbot = (bf16*)take(1048576);
  float* dtab = (float*)take(2560);
  bf16* wpTb = (bf16*)take(65536);
  float* LE = (float*)take(2359296);
  float* lr2 = (float*)take(262144);
  float* cs1 = (float*)take(1048576);
  bf16* p12 = (bf16*)take(1048576);
  float* c12 = (float*)take(2097152);
  bf16* cb = (bf16*)take(1048576);
  float* G12 = (float*)take(2097152);
  float* ss2 = (float*)take(2048);

  k_prep<<<2048, 256, 0, stream>>>(sv, Wl, Wr, Wg1, Wg2, de, Wd, bd, bl, br, bg1, bg2,
                                   Wp, u1b, wext, bext, wgbot, dtab, wpTb);
  // LE = u @ [Wl|Wr|Wg1t|Wg2t] + [bl|br|bg1|bg2]
  k_gemm<<<dim3(18, 8, 1), 256, 0, stream>>>(u1b, 512, 0, wext, 1152, 0, LE, 1152, 0,
                                             bext, 512, nullptr, 0, 0, nullptr);
  // pair1 (1024-thr probe): cs1 = add_scores(pair_scores(u), span_scores); + copy
  k_pair64<<<dim3(2, 128), 1024, 0, stream>>>(u1b, sv, wpTb, LE, 1152, dtab, sb,
                                              sscore, Wo, bo, cs1, asv, out_all, 1);
  // p1,p2
  k_softmax<<<1024, 64, 0, stream>>>(cs1, p12);
  // c1,c2 = [p1;p2] @ u ; side-output cb (bf16, z-layout)
  k_gemm<<<dim3(8, 16, 1), 256, 0, stream>>>(p12, 512, 0, u1b, 512, 0, c12, 512, 0,
                                             nullptr, 512, nullptr, 0, 0, cb);
  // G = c @ Wg_bot + E
  k_gemm<<<dim3(8, 8, 2), 256, 0, stream>>>(cb, 512, 262144, wgbot, 512, 262144,
                                            G12, 512, 262144, nullptr, 512,
                                            LE + 128, 512, 1152, nullptr);
  // update + u2 bf16 + ss2 + lr2 + scatter (fused)
  k_mid2<<<512, 512, 0, stream>>>(sv, c12, G12, Wpr, bpr, wext, 1152, bext, pi, sl,
                                  out_upd, u2b, ss2, lr2, out_all);
  // pair2 (control): cs -> out_cs
  k_pair2<<<dim3(2, 128), 512, 0, stream>>>(u2b, out_upd, wpTb, lr2, 128, dtab, sb,
                                            ss2, Wo, bo, out_cs);
}

// Round 16
// 136.749 us; speedup vs baseline: 1.0813x; 1.0813x over previous
//
#include <hip/hip_runtime.h>
#include <hip/hip_bf16.h>

// ModuleCorefProp2: coref propagation, B=1, K=512, N=16384, D=512, H=64, NB=10, 1 iter.
// R16 = R14 exactly (best: 137.0us; 512-thr k_pair64 + k_pair2) with one cleanup:
// k_softmax consolidated to 512 WGs x 128 thr (wave0=p1, wave1=p2 share one row read).
// R15's 1024-thr pair probe regressed (67us) and is reverted.

typedef __bf16 bf16;
typedef bf16 bf16x8 __attribute__((ext_vector_type(8)));
typedef float f32x4 __attribute__((ext_vector_type(4)));
typedef float f32x16 __attribute__((ext_vector_type(16)));

#define MFMA16(a, b, c) __builtin_amdgcn_mfma_f32_16x16x32_bf16((a), (b), (c), 0, 0, 0)
#define MFMA32(a, b, c) __builtin_amdgcn_mfma_f32_32x32x16_bf16((a), (b), (c), 0, 0, 0)

__device__ __forceinline__ void gll16(const bf16* g, bf16* lds) {
  __builtin_amdgcn_global_load_lds(
      (const __attribute__((address_space(1))) unsigned int*)g,
      (__attribute__((address_space(3))) unsigned int*)lds, 16, 0, 0);
}

// ---------------------------------------------------------------- prep
__global__ void k_prep(const float* __restrict__ sv,
                       const float* __restrict__ Wl, const float* __restrict__ Wr,
                       const float* __restrict__ Wg1, const float* __restrict__ Wg2,
                       const float* __restrict__ de, const float* __restrict__ Wd,
                       const float* __restrict__ bd, const float* __restrict__ bl,
                       const float* __restrict__ br, const float* __restrict__ bg1,
                       const float* __restrict__ bg2, const float* __restrict__ Wp,
                       bf16* __restrict__ u1, bf16* __restrict__ wext,
                       float* __restrict__ bext, bf16* __restrict__ wgbot,
                       float* __restrict__ dtab, bf16* __restrict__ wpTb)
{
  const int total = 262144 + 589824 + 1152 + 524288 + 640 + 32768;
  for (int idx0 = blockIdx.x * 256 + threadIdx.x; idx0 < total; idx0 += 2048 * 256) {
    int k = idx0;
    if (k < 262144) {                 // u -> bf16
      u1[k] = (bf16)sv[k];
      continue;
    }
    k -= 262144;
    if (k < 589824) {                 // wext = [Wl|Wr|Wg1top|Wg2top] bf16 [512][1152]
      int d = k / 1152, n = k % 1152;
      float v;
      if (n < 64) v = Wl[d * 64 + n];
      else if (n < 128) v = Wr[d * 64 + n - 64];
      else if (n < 640) v = Wg1[d * 512 + (n - 128)];
      else v = Wg2[d * 512 + (n - 640)];
      wext[k] = (bf16)v;
      continue;
    }
    k -= 589824;
    if (k < 1152) {                   // bext = [bl|br|bg1|bg2]
      float v;
      if (k < 64) v = bl[k];
      else if (k < 128) v = br[k - 64];
      else if (k < 640) v = bg1[k - 128];
      else v = bg2[k - 640];
      bext[k] = v;
      continue;
    }
    k -= 1152;
    if (k < 524288) {                 // wgbot bf16 [2][512][512] (bottom halves)
      wgbot[k] = (bf16)((k < 262144) ? Wg1[262144 + k] : Wg2[k]);
      continue;
    }
    k -= 524288;
    if (k < 640) {                    // dtab[NB][64] = dist_emb@Wd + bd
      int b_ = k >> 6, h = k & 63;
      float s = bd[h];
      for (int e = 0; e < 64; ++e) s += de[b_ * 64 + e] * Wd[e * 64 + h];
      dtab[k] = s;
      continue;
    }
    k -= 640;
    {                                 // wpTb[h][d] = Wp[d][h], bf16 [64][512]
      int h = k >> 9, d = k & 511;
      wpTb[k] = (bf16)Wp[d * 64 + h];
    }
  }
}

// ---------------------------------------------------------------- generic GEMM
__global__ __launch_bounds__(256, 2) void k_gemm(
    const bf16* __restrict__ A, int lda, long asz,
    const bf16* __restrict__ B, int ldb, long bsz,
    float* __restrict__ C, int ldc, long csz,
    const float* __restrict__ bias, int K,
    const float* __restrict__ addm, long addm_zs, int addm_ld,
    bf16* __restrict__ xout)
{
  __shared__ bf16 As[64 * 40];
  __shared__ bf16 Bs[64 * 40];
  const int t = threadIdx.x, lane = t & 63, wave = t >> 6;
  const int tc = blockIdx.x, tr = blockIdx.y, z = blockIdx.z;
  A += (long)z * asz; B += (long)z * bsz; C += (long)z * csz;
  const int wr = wave >> 1, wc = wave & 1;
  const int arow = t >> 2, aslot = t & 3;
  const int s = lane >> 4, rr = lane & 15;
  f32x4 acc00 = {}, acc01 = {}, acc10 = {}, acc11 = {};
  const int nk = K >> 5;
  for (int kk = 0; kk < nk; ++kk) {
    __syncthreads();
    *(uint4*)&As[arow * 40 + aslot * 8] =
        *(const uint4*)(A + (long)(tr * 64 + arow) * lda + kk * 32 + aslot * 8);
    {
      const bf16* bsrc = B + (long)(kk * 32 + aslot * 8) * ldb + tc * 64 + arow;
      bf16x8 tv;
#pragma unroll
      for (int e = 0; e < 8; ++e) tv[e] = bsrc[(long)e * ldb];
      *(bf16x8*)&Bs[arow * 40 + aslot * 8] = tv;
    }
    __syncthreads();
    bf16x8 a0 = *(const bf16x8*)&As[(wr * 32 + rr) * 40 + s * 8];
    bf16x8 a1 = *(const bf16x8*)&As[(wr * 32 + 16 + rr) * 40 + s * 8];
    bf16x8 b0 = *(const bf16x8*)&Bs[(wc * 32 + rr) * 40 + s * 8];
    bf16x8 b1 = *(const bf16x8*)&Bs[(wc * 32 + 16 + rr) * 40 + s * 8];
    acc00 = MFMA16(a0, b0, acc00);
    acc01 = MFMA16(a0, b1, acc01);
    acc10 = MFMA16(a1, b0, acc10);
    acc11 = MFMA16(a1, b1, acc11);
  }
#pragma unroll
  for (int mf = 0; mf < 2; ++mf) {
#pragma unroll
    for (int nf = 0; nf < 2; ++nf) {
      f32x4 v = mf == 0 ? (nf == 0 ? acc00 : acc01) : (nf == 0 ? acc10 : acc11);
      int col = tc * 64 + wc * 32 + nf * 16 + rr;
      float bi = bias ? bias[col] : 0.f;
      int row0 = tr * 64 + wr * 32 + mf * 16 + s * 4;
#pragma unroll
      for (int r = 0; r < 4; ++r) {
        int row = row0 + r;
        float val = v[r] + bi;
        if (addm) val += addm[z * addm_zs + (long)row * addm_ld + col];
        C[(long)row * ldc + col] = val;
        if (xout) xout[(long)row * 512 + col] = (bf16)val;
      }
    }
  }
}

// ---------------------------------------------------------------- pair64 (512 thr, proven)
__global__ __launch_bounds__(512, 1) void k_pair64(
    const bf16* __restrict__ Ubf, const float* __restrict__ Uf,
    const bf16* __restrict__ wpTb, const float* __restrict__ LR, int ldlr,
    const float* __restrict__ dtabg, const int* __restrict__ sb,
    const float* __restrict__ ss, const float* __restrict__ Wo,
    const float* __restrict__ bo, float* __restrict__ cs,
    const float* __restrict__ copysrc, float* __restrict__ copydst, int docopy)
{
  __shared__ bf16 Apan[2][256 * 64];   // 2 x 32KB
  __shared__ bf16 Bpan[2][256 * 64];   // 2 x 32KB
  __shared__ float dtsp[10 * 68];
  __shared__ int sbt[256];

  const int t = threadIdx.x;
  const int l = t & 63;
  const int w = t >> 6;
  const int wm = w >> 1, wn = w & 1;
  const int hi = l >> 5, l31 = l & 31;
  const int jb = blockIdx.x;           // 0..1
  const int mt = blockIdx.y;           // 0..127
  const int i0 = mt * 4;
  const int i = i0 + wm;

  for (int idx = t; idx < 640; idx += 512)
    dtsp[(idx >> 6) * 68 + (idx & 63)] = dtabg[idx];
  if (t < 256) sbt[t] = sb[jb * 256 + t];

  const bf16* bsrcq[4];
  bf16* bdstq[4];
#pragma unroll
  for (int q = 0; q < 4; ++q) {
    int u = q * 512 + t;
    int r = u >> 3, c = u & 7;
    bsrcq[q] = Ubf + (long)(jb * 256 + r) * 512 + ((c ^ (r & 7)) * 8);
    bdstq[q] = &Bpan[0][0] + q * 4096 + w * 512;
  }
  const float* uapq[4];
  const bf16* wppq[4];
  int awbq[4];
#pragma unroll
  for (int q = 0; q < 4; ++q) {
    int u = q * 512 + t;
    int m = u >> 3, c = u & 7;
    int koff = (c ^ (m & 7)) * 8;
    uapq[q] = Uf + (long)(i0 + (m >> 6)) * 512 + koff;
    wppq[q] = wpTb + (long)(m & 63) * 512 + koff;
    awbq[q] = m * 128 + c * 16;
  }

  int aoff[2][4], boff[4][4];
#pragma unroll
  for (int rf = 0; rf < 2; ++rf)
#pragma unroll
    for (int ks = 0; ks < 4; ++ks) {
      int r = wm * 64 + rf * 32 + l31;
      aoff[rf][ks] = r * 128 + (((ks * 2 + hi) ^ (r & 7)) * 16);
    }
#pragma unroll
  for (int cf = 0; cf < 4; ++cf)
#pragma unroll
    for (int ks = 0; ks < 4; ++ks) {
      int r = wn * 128 + cf * 32 + l31;
      boff[cf][ks] = r * 128 + (((ks * 2 + hi) ^ (r & 7)) * 16);
    }

  {
#pragma unroll
    for (int q = 0; q < 4; ++q) gll16(bsrcq[q], bdstq[q]);
#pragma unroll
    for (int q = 0; q < 4; ++q) {
      float4 f0 = *(const float4*)uapq[q];
      float4 f1 = *(const float4*)(uapq[q] + 4);
      bf16x8 wv = *(const bf16x8*)wppq[q];
      bf16x8 v;
#pragma unroll
      for (int e = 0; e < 4; ++e) {
        v[e] = (bf16)(f0[e] * (float)wv[e]);
        v[e + 4] = (bf16)(f1[e] * (float)wv[e + 4]);
      }
      *(bf16x8*)((char*)&Apan[0][0] + awbq[q]) = v;
    }
  }
  asm volatile("s_waitcnt vmcnt(0)");
  __syncthreads();

  f32x16 acc[2][4] = {};

  for (int kc = 0; kc < 8; ++kc) {
    const int cur = kc & 1;
    float4 nf0[4], nf1[4];
    bf16x8 nwv[4];
    if (kc < 7) {
#pragma unroll
      for (int q = 0; q < 4; ++q)
        gll16(bsrcq[q] + (kc + 1) * 64, bdstq[q] + (cur ^ 1) * 16384);
#pragma unroll
      for (int q = 0; q < 4; ++q) {
        nf0[q] = *(const float4*)(uapq[q] + (kc + 1) * 64);
        nf1[q] = *(const float4*)(uapq[q] + (kc + 1) * 64 + 4);
        nwv[q] = *(const bf16x8*)(wppq[q] + (kc + 1) * 64);
      }
    }
    const char* Ab = (const char*)&Apan[cur][0];
    const char* Bb = (const char*)&Bpan[cur][0];
#pragma unroll
    for (int ks = 0; ks < 4; ++ks) {
      bf16x8 af0 = *(const bf16x8*)(Ab + aoff[0][ks]);
      bf16x8 af1 = *(const bf16x8*)(Ab + aoff[1][ks]);
      bf16x8 bf0 = *(const bf16x8*)(Bb + boff[0][ks]);
      bf16x8 bf1 = *(const bf16x8*)(Bb + boff[1][ks]);
      bf16x8 bf2 = *(const bf16x8*)(Bb + boff[2][ks]);
      bf16x8 bf3 = *(const bf16x8*)(Bb + boff[3][ks]);
      __builtin_amdgcn_s_setprio(1);
      acc[0][0] = MFMA32(af0, bf0, acc[0][0]);
      acc[0][1] = MFMA32(af0, bf1, acc[0][1]);
      acc[0][2] = MFMA32(af0, bf2, acc[0][2]);
      acc[0][3] = MFMA32(af0, bf3, acc[0][3]);
      acc[1][0] = MFMA32(af1, bf0, acc[1][0]);
      acc[1][1] = MFMA32(af1, bf1, acc[1][1]);
      acc[1][2] = MFMA32(af1, bf2, acc[1][2]);
      acc[1][3] = MFMA32(af1, bf3, acc[1][3]);
      __builtin_amdgcn_s_setprio(0);
    }
    if (kc < 7) {
      asm volatile("s_waitcnt vmcnt(0)");
      char* Ad = (char*)&Apan[cur ^ 1][0];
#pragma unroll
      for (int q = 0; q < 4; ++q) {
        bf16x8 v;
#pragma unroll
        for (int e = 0; e < 4; ++e) {
          v[e] = (bf16)(nf0[q][e] * (float)nwv[q][e]);
          v[e + 4] = (bf16)(nf1[q][e] * (float)nwv[q][e + 4]);
        }
        *(bf16x8*)(Ad + awbq[q]) = v;
      }
    }
    __syncthreads();
  }

  float4 wo_t[2][4], lf_t[2][4];
#pragma unroll
  for (int rf = 0; rf < 2; ++rf)
#pragma unroll
    for (int g = 0; g < 4; ++g) {
      wo_t[rf][g] = *(const float4*)&Wo[rf * 32 + 4 * hi + 8 * g];
      lf_t[rf][g] = *(const float4*)&LR[(long)i * ldlr + rf * 32 + 4 * hi + 8 * g];
    }
  const float ssi = ss[i];
  const int sbi = sb[i];
  const float bo0 = bo[0];
#pragma unroll
  for (int cf = 0; cf < 4; ++cf) {
    int jl = wn * 128 + cf * 32 + l31;
    int j = jb * 256 + jl;
    int dd = sbi - sbt[jl];
    int ad = dd < 0 ? -dd : dd;
    int bkt = ad < 5 ? ad : (31 - __clz(ad)) + 3;
    bkt = bkt > 9 ? 9 : bkt;
    float ssj = ss[j];
    float sum = 0.f;
#pragma unroll
    for (int rf = 0; rf < 2; ++rf) {
#pragma unroll
      for (int g = 0; g < 4; ++g) {
        float4 dt4 = *(const float4*)&dtsp[bkt * 68 + rf * 32 + 4 * hi + 8 * g];
        float4 rt4 = *(const float4*)&LR[(long)j * ldlr + 64 + rf * 32 + 4 * hi + 8 * g];
#pragma unroll
        for (int e = 0; e < 4; ++e) {
          float v = acc[rf][cf][g * 4 + e] + lf_t[rf][g][e] + rt4[e] + dt4[e];
          v = fmaxf(v, 0.f);
          sum += v * wo_t[rf][g][e];
        }
      }
    }
    sum += __shfl_xor(sum, 32);
    float val = (j == i) ? 0.f : (sum + bo0 + ssi + ssj);
    if (hi == 0) cs[(long)i * 512 + j] = val;
  }

  if (docopy) {
    const float4* s4 = (const float4*)copysrc;
    float4* d4 = (float4*)copydst;
    int idx = (mt * 2 + jb) * 512 + t;
#pragma unroll
    for (int q = 0; q < 16; ++q)
      d4[(long)q * 131072 + idx] = s4[(long)q * 131072 + idx];
  }
}

// ---------------------------------------------------------------- pair2 (R12 proven)
#define P2_BUILD(DST, A00, A01, A10, A11, W0, W1)                \
  {                                                              \
    bf16x8 v0, v1;                                               \
    _Pragma("unroll") for (int e = 0; e < 4; ++e) {              \
      v0[e] = (bf16)((A00)[e] * (float)(W0)[e]);                 \
      v0[e + 4] = (bf16)((A01)[e] * (float)(W0)[e + 4]);         \
      v1[e] = (bf16)((A10)[e] * (float)(W1)[e]);                 \
      v1[e + 4] = (bf16)((A11)[e] * (float)(W1)[e + 4]);         \
    }                                                            \
    *(bf16x8*)((DST) + awb0) = v0;                               \
    *(bf16x8*)((DST) + awb1) = v1;                               \
  }

#define P2_ITER(KC, bA00, bA01, bA10, bA11, bW0, bW1, rA00, rA01, rA10, rA11, rW0, rW1) \
  {                                                                                     \
    const int bcur = (KC) % 3, bnxt = ((KC) + 1) % 3, bpre = ((KC) + 2) % 3;            \
    asm volatile("s_waitcnt lgkmcnt(0)");                                               \
    asm volatile("s_waitcnt vmcnt(14)");                                                \
    __builtin_amdgcn_sched_barrier(0);                                                  \
    __builtin_amdgcn_s_barrier();                                                       \
    const char* Ab = Abase + bcur * 16384;                                              \
    const char* Bb = Bbase + bcur * 16384;                                              \
    _Pragma("unroll") for (int ks = 0; ks < 2; ++ks) {                                  \
      bf16x8 af0 = *(const bf16x8*)(Ab + aoff[0][ks]);                                  \
      bf16x8 af1 = *(const bf16x8*)(Ab + aoff[1][ks]);                                  \
      bf16x8 bf0 = *(const bf16x8*)(Bb + boff[0][ks]);                                  \
      bf16x8 bf1 = *(const bf16x8*)(Bb + boff[1][ks]);                                  \
      bf16x8 bf2 = *(const bf16x8*)(Bb + boff[2][ks]);                                  \
      bf16x8 bf3 = *(const bf16x8*)(Bb + boff[3][ks]);                                  \
      __builtin_amdgcn_s_setprio(1);                                                    \
      acc[0][0] = MFMA32(af0, bf0, acc[0][0]);                                          \
      acc[0][1] = MFMA32(af0, bf1, acc[0][1]);                                          \
      acc[0][2] = MFMA32(af0, bf2, acc[0][2]);                                          \
      acc[0][3] = MFMA32(af0, bf3, acc[0][3]);                                          \
      acc[1][0] = MFMA32(af1, bf0, acc[1][0]);                                          \
      acc[1][1] = MFMA32(af1, bf1, acc[1][1]);                                          \
      acc[1][2] = MFMA32(af1, bf2, acc[1][2]);                                          \
      acc[1][3] = MFMA32(af1, bf3, acc[1][3]);                                          \
      __builtin_amdgcn_s_setprio(0);                                                    \
    }                                                                                   \
    if ((KC) < 15) { P2_BUILD(Abase + bnxt * 16384, bA00, bA01, bA10, bA11, bW0, bW1) } \
    if ((KC) < 14) {                                                                    \
      bf16* Bd = (bf16*)(Bbase + bpre * 16384);                                         \
      gll16(bsrc0 + ((KC) + 2) * 32, Bd + w * 512);                                     \
      gll16(bsrc1 + ((KC) + 2) * 32, Bd + 4096 + w * 512);                              \
      rA00 = *(const float4*)(ua0p + ((KC) + 2) * 32);                                  \
      rA01 = *(const float4*)(ua0p + ((KC) + 2) * 32 + 4);                              \
      rA10 = *(const float4*)(ua1p + ((KC) + 2) * 32);                                  \
      rA11 = *(const float4*)(ua1p + ((KC) + 2) * 32 + 4);                              \
      rW0 = *(const bf16x8*)(wp0p + ((KC) + 2) * 32);                                   \
      rW1 = *(const bf16x8*)(wp1p + ((KC) + 2) * 32);                                   \
    }                                                                                   \
  }

__global__ __launch_bounds__(512, 1) void k_pair2(
    const bf16* __restrict__ Ubf, const float* __restrict__ Uf,
    const bf16* __restrict__ wpTb, const float* __restrict__ LR, int ldlr,
    const float* __restrict__ dtabg, const int* __restrict__ sb,
    const float* __restrict__ ss, const float* __restrict__ Wo,
    const float* __restrict__ bo, float* __restrict__ cs)
{
  __shared__ bf16 Apan[3][256 * 32];
  __shared__ bf16 Bpan[3][256 * 32];
  __shared__ float dtsp[10 * 68];
  __shared__ int sbt[256];

  const int t = threadIdx.x;
  const int l = t & 63;
  const int w = t >> 6;
  const int wm = w >> 1, wn = w & 1;
  const int hi = l >> 5, l31 = l & 31;
  const int jb = blockIdx.x;
  const int mt = blockIdx.y;
  const int i0 = mt * 4;
  const int i = i0 + wm;

  for (int idx = t; idx < 640; idx += 512)
    dtsp[(idx >> 6) * 68 + (idx & 63)] = dtabg[idx];
  if (t < 256) sbt[t] = sb[jb * 256 + t];

  const bf16 *bsrc0, *bsrc1;
  {
    int r0 = t >> 2, c0 = t & 3;
    int r1 = 128 + (t >> 2);
    bsrc0 = Ubf + (long)(jb * 256 + r0) * 512 + ((c0 ^ ((r0 >> 1) & 3)) * 8);
    bsrc1 = Ubf + (long)(jb * 256 + r1) * 512 + ((c0 ^ ((r1 >> 1) & 3)) * 8);
  }
  const int ar0 = t >> 2, ar1 = 128 + (t >> 2), as0 = t & 3;
  const int awb0 = ar0 * 64 + ((as0 ^ ((ar0 >> 1) & 3)) * 16);
  const int awb1 = ar1 * 64 + ((as0 ^ ((ar1 >> 1) & 3)) * 16);
  const float* ua0p = Uf + (long)(i0 + (ar0 >> 6)) * 512 + as0 * 8;
  const float* ua1p = Uf + (long)(i0 + (ar1 >> 6)) * 512 + as0 * 8;
  const bf16* wp0p = wpTb + (long)(ar0 & 63) * 512 + as0 * 8;
  const bf16* wp1p = wpTb + (long)(ar1 & 63) * 512 + as0 * 8;

  int aoff[2][2], boff[4][2];
#pragma unroll
  for (int rf = 0; rf < 2; ++rf)
#pragma unroll
    for (int ks = 0; ks < 2; ++ks) {
      int r = wm * 64 + rf * 32 + l31;
      aoff[rf][ks] = r * 64 + (((ks * 2 + hi) ^ ((r >> 1) & 3)) * 16);
    }
#pragma unroll
  for (int cf = 0; cf < 4; ++cf)
#pragma unroll
    for (int ks = 0; ks < 2; ++ks) {
      int r = wn * 128 + cf * 32 + l31;
      boff[cf][ks] = r * 64 + (((ks * 2 + hi) ^ ((r >> 1) & 3)) * 16);
    }

  char* Abase = (char*)&Apan[0][0];
  char* Bbase = (char*)&Bpan[0][0];

  float4 aA00, aA01, aA10, aA11; bf16x8 wA0, wA1;
  float4 aB00, aB01, aB10, aB11; bf16x8 wB0, wB1;
  gll16(bsrc0, (bf16*)Bbase + w * 512);
  gll16(bsrc1, (bf16*)Bbase + 4096 + w * 512);
  aA00 = *(const float4*)ua0p;        aA01 = *(const float4*)(ua0p + 4);
  aA10 = *(const float4*)ua1p;        aA11 = *(const float4*)(ua1p + 4);
  wA0 = *(const bf16x8*)wp0p;         wA1 = *(const bf16x8*)wp1p;
  gll16(bsrc0 + 32, (bf16*)(Bbase + 16384) + w * 512);
  gll16(bsrc1 + 32, (bf16*)(Bbase + 16384) + 4096 + w * 512);
  aB00 = *(const float4*)(ua0p + 32); aB01 = *(const float4*)(ua0p + 36);
  aB10 = *(const float4*)(ua1p + 32); aB11 = *(const float4*)(ua1p + 36);
  wB0 = *(const bf16x8*)(wp0p + 32);  wB1 = *(const bf16x8*)(wp1p + 32);
  P2_BUILD(Abase, aA00, aA01, aA10, aA11, wA0, wA1)

  f32x16 acc[2][4] = {};

  for (int kq = 0; kq < 8; ++kq) {
    const int kc = kq * 2;
    P2_ITER(kc, aB00, aB01, aB10, aB11, wB0, wB1,
            aA00, aA01, aA10, aA11, wA0, wA1)
    P2_ITER(kc + 1, aA00, aA01, aA10, aA11, wA0, wA1,
            aB00, aB01, aB10, aB11, wB0, wB1)
  }

  float4 wo_t[2][4], lf_t[2][4];
#pragma unroll
  for (int rf = 0; rf < 2; ++rf)
#pragma unroll
    for (int g = 0; g < 4; ++g) {
      wo_t[rf][g] = *(const float4*)&Wo[rf * 32 + 4 * hi + 8 * g];
      lf_t[rf][g] = *(const float4*)&LR[(long)i * ldlr + rf * 32 + 4 * hi + 8 * g];
    }
  const float ssi = ss[i];
  const int sbi = sb[i];
  const float bo0 = bo[0];
#pragma unroll
  for (int cf = 0; cf < 4; ++cf) {
    int jl = wn * 128 + cf * 32 + l31;
    int j = jb * 256 + jl;
    int dd = sbi - sbt[jl];
    int ad = dd < 0 ? -dd : dd;
    int bkt = ad < 5 ? ad : (31 - __clz(ad)) + 3;
    bkt = bkt > 9 ? 9 : bkt;
    float ssj = ss[j];
    float sum = 0.f;
#pragma unroll
    for (int rf = 0; rf < 2; ++rf) {
#pragma unroll
      for (int g = 0; g < 4; ++g) {
        float4 dt4 = *(const float4*)&dtsp[bkt * 68 + rf * 32 + 4 * hi + 8 * g];
        float4 rt4 = *(const float4*)&LR[(long)j * ldlr + 64 + rf * 32 + 4 * hi + 8 * g];
#pragma unroll
        for (int e = 0; e < 4; ++e) {
          float v = acc[rf][cf][g * 4 + e] + lf_t[rf][g][e] + rt4[e] + dt4[e];
          v = fmaxf(v, 0.f);
          sum += v * wo_t[rf][g][e];
        }
      }
    }
    sum += __shfl_xor(sum, 32);
    float val = (j == i) ? 0.f : (sum + bo0 + ssi + ssj);
    if (hi == 0) cs[(long)i * 512 + j] = val;
  }
}

// ---------------------------------------------------------------- masked softmax rows
// 512 WGs x 128 thr: wave 0 = p1 (mask j<i), wave 1 = p2 (mask j>i); shared row read.
__global__ __launch_bounds__(128) void k_softmax(const float* __restrict__ cs,
                                                 bf16* __restrict__ p12)
{
  int i = blockIdx.x, kind = threadIdx.x >> 6, lane = threadIdx.x & 63;
  const float* row = cs + (long)i * 512;
  float v[8];
  float4 x0 = *(const float4*)(row + lane * 8);
  float4 x1 = *(const float4*)(row + lane * 8 + 4);
  v[0] = x0.x; v[1] = x0.y; v[2] = x0.z; v[3] = x0.w;
  v[4] = x1.x; v[5] = x1.y; v[6] = x1.z; v[7] = x1.w;
  bool any = (kind == 0) ? (i > 0) : (i < 511);
  bf16x8 ov;
  if (!any) {
    float u = 1.0f / 512.0f;
#pragma unroll
    for (int e = 0; e < 8; ++e) ov[e] = (bf16)u;
  } else {
    float m = -3.4e38f;
#pragma unroll
    for (int e = 0; e < 8; ++e) {
      int jj = lane * 8 + e;
      bool valid = (kind == 0) ? (jj < i) : (jj > i);
      if (valid) m = fmaxf(m, v[e]);
    }
    m = fmaxf(m, __shfl_xor(m, 1));  m = fmaxf(m, __shfl_xor(m, 2));
    m = fmaxf(m, __shfl_xor(m, 4));  m = fmaxf(m, __shfl_xor(m, 8));
    m = fmaxf(m, __shfl_xor(m, 16)); m = fmaxf(m, __shfl_xor(m, 32));
    float p[8]; float ssum = 0.f;
#pragma unroll
    for (int e = 0; e < 8; ++e) {
      int jj = lane * 8 + e;
      bool valid = (kind == 0) ? (jj < i) : (jj > i);
      p[e] = valid ? __expf(v[e] - m) : 0.f;
      ssum += p[e];
    }
    ssum += __shfl_xor(ssum, 1);  ssum += __shfl_xor(ssum, 2);
    ssum += __shfl_xor(ssum, 4);  ssum += __shfl_xor(ssum, 8);
    ssum += __shfl_xor(ssum, 16); ssum += __shfl_xor(ssum, 32);
    float inv = 1.0f / ssum;
#pragma unroll
    for (int e = 0; e < 8; ++e) ov[e] = (bf16)(p[e] * inv);
  }
  *(bf16x8*)(p12 + ((long)kind * 512 + i) * 512 + lane * 8) = ov;
}

// ---------------------------------------------------------------- mid2: gate+ss2+lr2+scatter
__global__ __launch_bounds__(512) void k_mid2(
    const float* __restrict__ sv, const float* __restrict__ c12,
    const float* __restrict__ G12, const float* __restrict__ Wpr,
    const float* __restrict__ bpr, const bf16* __restrict__ wext, int ldw,
    const float* __restrict__ bext, const int* __restrict__ pi,
    const int* __restrict__ sl, float* __restrict__ upd,
    bf16* __restrict__ u2, float* __restrict__ ss2,
    float* __restrict__ lr2, float* __restrict__ out_all)
{
  __shared__ float upl[512];
  __shared__ float red[8];
  __shared__ float part2[4][128];
  const int i = blockIdx.x;
  const int t = threadIdx.x;
  const long ii = (long)i * 512 + t;

  float u = sv[ii], c1 = c12[ii], c2 = c12[262144 + ii];
  float g1 = 1.f / (1.f + __expf(-G12[ii]));
  float g2 = 1.f / (1.f + __expf(-G12[262144 + ii]));
  float up = g1 * u + (1.f - g1) * c1 + g2 * u + (1.f - g2) * c2;
  upd[ii] = up;
  u2[ii] = (bf16)up;
  upl[t] = up;
  if (i < sl[0]) out_all[(long)pi[i] * 512 + t] = up;

  float pd = up * Wpr[t];
  pd += __shfl_xor(pd, 1);  pd += __shfl_xor(pd, 2);  pd += __shfl_xor(pd, 4);
  pd += __shfl_xor(pd, 8);  pd += __shfl_xor(pd, 16); pd += __shfl_xor(pd, 32);
  if ((t & 63) == 0) red[t >> 6] = pd;
  __syncthreads();
  if (t == 0) {
    float s = 0.f;
#pragma unroll
    for (int e = 0; e < 8; ++e) s += red[e];
    ss2[i] = s + bpr[0];
  }

  const int n = t & 127, part = t >> 7;
  float s = 0.f;
  const int d0 = part * 128;
#pragma unroll 4
  for (int d2 = 0; d2 < 128; ++d2)
    s += upl[d0 + d2] * (float)wext[(long)(d0 + d2) * ldw + n];
  part2[part][n] = s;
  __syncthreads();
  if (t < 128)
    lr2[(long)i * 128 + t] =
        part2[0][t] + part2[1][t] + part2[2][t] + part2[3][t] + bext[t];
}

// ---------------------------------------------------------------- launch
extern "C" void kernel_launch(void* const* d_in, const int* in_sizes, int n_in,
                              void* d_out, int out_size, void* d_ws, size_t ws_size,
                              hipStream_t stream)
{
  const float* asv = (const float*)d_in[0];
  const float* sv = (const float*)d_in[1];
  const int* sb = (const int*)d_in[2];
  const float* sscore = (const float*)d_in[5];
  const int* pi = (const int*)d_in[6];
  const int* sl = (const int*)d_in[7];
  const float* Wl = (const float*)d_in[9];
  const float* bl = (const float*)d_in[10];
  const float* Wr = (const float*)d_in[11];
  const float* br = (const float*)d_in[12];
  const float* Wp = (const float*)d_in[13];
  const float* de = (const float*)d_in[14];
  const float* Wd = (const float*)d_in[15];
  const float* bd = (const float*)d_in[16];
  const float* Wo = (const float*)d_in[17];
  const float* bo = (const float*)d_in[18];
  const float* Wg1 = (const float*)d_in[19];
  const float* bg1 = (const float*)d_in[20];
  const float* Wg2 = (const float*)d_in[21];
  const float* bg2 = (const float*)d_in[22];
  const float* Wpr = (const float*)d_in[23];
  const float* bpr = (const float*)d_in[24];

  float* out_all = (float*)d_out;
  float* out_upd = out_all + 8388608;
  float* out_cs = out_all + 8650752;

  char* w = (char*)d_ws;
  size_t off = 0;
  auto take = [&](size_t bytes) -> void* {
    void* p = w + off;
    off = (off + bytes + 255) & ~(size_t)255;
    return p;
  };
  bf16* u1b = (bf16*)take(524288);
  bf16* u2b = (bf16*)take(524288);
  bf16* wext = (bf16*)take(1179648);
  float* bext = (float*)take(4608);
  bf16* wgbot = (bf16*)take(1048576);
  float* dtab = (float*)take(2560);
  bf16* wpTb = (bf16*)take(65536);
  float* LE = (float*)take(2359296);
  float* lr2 = (float*)take(262144);
  float* cs1 = (float*)take(1048576);
  bf16* p12 = (bf16*)take(1048576);
  float* c12 = (float*)take(2097152);
  bf16* cb = (bf16*)take(1048576);
  float* G12 = (float*)take(2097152);
  float* ss2 = (float*)take(2048);

  k_prep<<<2048, 256, 0, stream>>>(sv, Wl, Wr, Wg1, Wg2, de, Wd, bd, bl, br, bg1, bg2,
                                   Wp, u1b, wext, bext, wgbot, dtab, wpTb);
  // LE = u @ [Wl|Wr|Wg1t|Wg2t] + [bl|br|bg1|bg2]
  k_gemm<<<dim3(18, 8, 1), 256, 0, stream>>>(u1b, 512, 0, wext, 1152, 0, LE, 1152, 0,
                                             bext, 512, nullptr, 0, 0, nullptr);
  // pair1: cs1 = add_scores(pair_scores(u), span_scores); + full all_out copy
  k_pair64<<<dim3(2, 128), 512, 0, stream>>>(u1b, sv, wpTb, LE, 1152, dtab, sb,
                                             sscore, Wo, bo, cs1, asv, out_all, 1);
  // p1,p2 (consolidated: one WG per row, 2 waves)
  k_softmax<<<512, 128, 0, stream>>>(cs1, p12);
  // c1,c2 = [p1;p2] @ u ; side-output cb (bf16, z-layout)
  k_gemm<<<dim3(8, 16, 1), 256, 0, stream>>>(p12, 512, 0, u1b, 512, 0, c12, 512, 0,
                                             nullptr, 512, nullptr, 0, 0, cb);
  // G = c @ Wg_bot + E
  k_gemm<<<dim3(8, 8, 2), 256, 0, stream>>>(cb, 512, 262144, wgbot, 512, 262144,
                                            G12, 512, 262144, nullptr, 512,
                                            LE + 128, 512, 1152, nullptr);
  // update + u2 bf16 + ss2 + lr2 + scatter (fused)
  k_mid2<<<512, 512, 0, stream>>>(sv, c12, G12, Wpr, bpr, wext, 1152, bext, pi, sl,
                                  out_upd, u2b, ss2, lr2, out_all);
  // pair2: cs -> out_cs
  k_pair2<<<dim3(2, 128), 512, 0, stream>>>(u2b, out_upd, wpTb, lr2, 128, dtab, sb,
                                            ss2, Wo, bo, out_cs);
}